// Round 2
// baseline (166.775 us; speedup 1.0000x reference)
//
#include <hip/hip_runtime.h>
#include <hip/hip_fp16.h>

// NeuronToSpatialGrid: out[b,e,p] = (sum_n w * F[b,n,e]) / (sum_n w + EPS),
//   w = exp(-||c_p - x_n||^2 * 50) = exp(-50 dx^2) * exp(-50 dy^2)   <-- separable!
// B=4, N=4096, E=256, P=64*64.  dx depends only on (gx, n): gx = p>>6 = m-tile index
// (constant per block).  dy depends only on (gy = p&63, n) -> precomputed EY table.

typedef __attribute__((ext_vector_type(8))) _Float16 half8;
typedef __attribute__((ext_vector_type(2))) _Float16 half2v;
typedef __attribute__((ext_vector_type(4))) float floatx4;

#define NB 4
#define NN 4096
#define NE 256
#define NP 4096

#if defined(__has_builtin)
#if __has_builtin(__builtin_amdgcn_fdot2)
#define HAVE_FDOT2 1
#endif
#endif

__device__ inline float sum8(half8 v, float s) {
#ifdef HAVE_FDOT2
    half2v one; one[0] = (_Float16)1.0f; one[1] = (_Float16)1.0f;
    half2v* p = (half2v*)&v;
#pragma unroll
    for (int j = 0; j < 4; j++) s = __builtin_amdgcn_fdot2(p[j], one, s, false);
#else
#pragma unroll
    for (int j = 0; j < 8; j++) s += (float)v[j];
#endif
    return s;
}

// ---------- kernel 1: features [B][N][E] f32 -> FT [B][E][N] f16 (k-contiguous B rows)
__global__ __launch_bounds__(256) void feat_transpose(const float* __restrict__ in,
                                                      __half* __restrict__ ft) {
    __shared__ float tile[32][33];
    const int b  = blockIdx.z;
    const int n0 = blockIdx.x * 32;
    const int e0 = blockIdx.y * 32;
    const int tx = threadIdx.x, ty = threadIdx.y;
#pragma unroll
    for (int i = ty; i < 32; i += 8)
        tile[i][tx] = in[(size_t)(b * NN + n0 + i) * NE + e0 + tx];
    __syncthreads();
#pragma unroll
    for (int i = ty; i < 32; i += 8)
        ft[(size_t)(b * NE + e0 + i) * NN + n0 + tx] = __float2half_rn(tile[tx][i]);
}

// ---------- kernel 2: EY in MFMA-A-fragment order.
// EYf index [b][kb(128)][rb(4)][quad(4)][fr(16)][j(8)] holds exp(-50*(r/63 - y_k)^2)
// with r = rb*16+fr, k = kb*32+quad*8+j.  A wave's frag load (lane = quad*16+fr,
// 16B each) is then one contiguous 1KB coalesced read.
__global__ __launch_bounds__(256) void eyf_kernel(const float* __restrict__ pos,
                                                  __half* __restrict__ EYf) {
    const int idx = blockIdx.x * 256 + threadIdx.x;   // 4*2^18 total
    const int j    = idx & 7;
    const int fr   = (idx >> 3) & 15;
    const int quad = (idx >> 7) & 3;
    const int rb   = (idx >> 9) & 3;
    const int kb   = (idx >> 11) & 127;
    const int b    = idx >> 18;
    const int r = rb * 16 + fr;
    const int k = kb * 32 + quad * 8 + j;
    const float y = pos[((size_t)b * NN + k) * 2 + 1];
    const float d = (float)r * (1.0f / 63.0f) - y;
    EYf[idx] = __float2half_rn(__expf(d * d * -50.0f));
}

// ---------- kernel 3: fused GEMM.  A-frags generated in registers (ex * ey),
// B through LDS.  grid 256 (1/CU), 512 threads (8 waves as 2m x 4n, wave tile 32x64).
__global__ __launch_bounds__(512, 2) void nw_gemm(const __half* __restrict__ FT,   // [B][E][N]
                                                  const __half* __restrict__ EYf,  // frag order
                                                  const float* __restrict__ pos,   // [B][N][2]
                                                  float* __restrict__ out) {       // [B][E][P]
    __shared__ __half Bt_s[256][40];      // 20 KB feature tile [e][k], stride 80B (16B-aligned, reads 2-way = free)
    __shared__ __half ex_s[NN];           // 8 KB: exp(-50*(gx - x_k)^2) for all k (gx const per block)
    __shared__ float S_s[64];

    const int bid = blockIdx.x;
    const int xcd = bid & 7;
    const int b   = xcd >> 1;
    const int mt  = (bid >> 3) + ((xcd & 1) << 5);   // 0..63 m-tile; gx index = mt
    const int m0  = mt * 64;
    const int tid = threadIdx.x;

    // --- ex_s: 4096 exps once per block (8/thread) ---
    {
        const float gxv = (float)mt * (1.0f / 63.0f);
        const float* pb = pos + (size_t)b * NN * 2;
#pragma unroll
        for (int k = tid; k < NN; k += 512) {
            float d = gxv - pb[2 * k];
            ex_s[k] = __float2half_rn(__expf(d * d * -50.0f));
        }
    }

    // --- B staging: thread -> e-row tid>>1, k-half (tid&1)*16 (32B/thread) ---
    const int brow = tid >> 1;
    const int bh   = tid & 1;
    const __half* bsrc = FT + ((size_t)b * NE + brow) * NN + bh * 16;

    // --- wave mapping: 8 waves as 2(m) x 4(n); wave tile 32x64 ---
    const int wave = tid >> 6, lane = tid & 63;
    const int g   = wave >> 2;            // m-group: rows g*32 .. g*32+31
    const int n_w = (wave & 3) * 64;
    const int fr = lane & 15, quad = lane >> 4;
    const int quad8 = quad * 8;

    // --- EY frag pointers: frag i covers rows g*32 + i*16 + fr ---
    const __half* eyb = EYf + ((size_t)b << 18) + quad * 128 + fr * 8;
    const __half* ey0p = eyb + (g * 2 + 0) * 512;   // + ks*64 per K-step
    const __half* ey1p = eyb + (g * 2 + 1) * 512;

    const bool sumwave = (wave & 3) == 0;   // waves 0 (rows 0..31) and 4 (rows 32..63)

    floatx4 acc[2][4] = {};
    float s0 = 0.f, s1 = 0.f;

    // initial prefetch (ks = 0)
    half8 ey0 = *(const half8*)(ey0p);
    half8 ey1 = *(const half8*)(ey1p);
    uint4 bv0 = *(const uint4*)(bsrc);
    uint4 bv1 = *(const uint4*)(bsrc + 8);

    __syncthreads();   // ex_s ready

    for (int ks = 0; ks < NN; ks += 32) {
        // stage B tile from prefetched regs
        *(uint4*)(&Bt_s[brow][bh * 16])     = bv0;
        *(uint4*)(&Bt_s[brow][bh * 16 + 8]) = bv1;

        // A-frags in registers: af[i][j] = ex[ks+quad*8+j] * EY[row i][same k]
        half8 ex8 = *(const half8*)(&ex_s[ks + quad8]);   // broadcast read (free)
        half8 af0 = ex8 * ey0;
        half8 af1 = ex8 * ey1;
        if (sumwave) { s0 = sum8(af0, s0); s1 = sum8(af1, s1); }

        __syncthreads();   // Bt ready

        // prefetch next iter (globals in flight across the MFMA block)
        if (ks + 32 < NN) {
            const int koff = (ks + 32) * 64;
            ey0 = *(const half8*)(ey0p + koff);
            ey1 = *(const half8*)(ey1p + koff);
            bv0 = *(const uint4*)(bsrc + ks + 32);
            bv1 = *(const uint4*)(bsrc + ks + 40);
        }

        half8 bf0 = *(const half8*)(&Bt_s[n_w + fr][quad8]);
        half8 bf1 = *(const half8*)(&Bt_s[n_w + 16 + fr][quad8]);
        half8 bf2 = *(const half8*)(&Bt_s[n_w + 32 + fr][quad8]);
        half8 bf3 = *(const half8*)(&Bt_s[n_w + 48 + fr][quad8]);

        acc[0][0] = __builtin_amdgcn_mfma_f32_16x16x32_f16(af0, bf0, acc[0][0], 0, 0, 0);
        acc[0][1] = __builtin_amdgcn_mfma_f32_16x16x32_f16(af0, bf1, acc[0][1], 0, 0, 0);
        acc[0][2] = __builtin_amdgcn_mfma_f32_16x16x32_f16(af0, bf2, acc[0][2], 0, 0, 0);
        acc[0][3] = __builtin_amdgcn_mfma_f32_16x16x32_f16(af0, bf3, acc[0][3], 0, 0, 0);
        acc[1][0] = __builtin_amdgcn_mfma_f32_16x16x32_f16(af1, bf0, acc[1][0], 0, 0, 0);
        acc[1][1] = __builtin_amdgcn_mfma_f32_16x16x32_f16(af1, bf1, acc[1][1], 0, 0, 0);
        acc[1][2] = __builtin_amdgcn_mfma_f32_16x16x32_f16(af1, bf2, acc[1][2], 0, 0, 0);
        acc[1][3] = __builtin_amdgcn_mfma_f32_16x16x32_f16(af1, bf3, acc[1][3], 0, 0, 0);

        __syncthreads();   // frag reads done -> Bt_s reusable
    }

    // --- row sums: reduce over quad (k was split quad*8 + 32Z across quads) ---
    if (sumwave) {
        s0 += __shfl_xor(s0, 16, 64); s0 += __shfl_xor(s0, 32, 64);
        s1 += __shfl_xor(s1, 16, 64); s1 += __shfl_xor(s1, 32, 64);
        if (quad == 0) {
            S_s[g * 32 + fr]      = 1.0f / (s0 + 1e-8f);
            S_s[g * 32 + 16 + fr] = 1.0f / (s1 + 1e-8f);
        }
    }
    __syncthreads();

    // --- epilogue: normalize, store float4 along p ---
    float* outb = out + (size_t)b * NE * NP;
    const int m_w = g * 32;
#pragma unroll
    for (int i = 0; i < 2; i++) {
        const int rbase = m_w + i * 16 + quad * 4;
        floatx4 sv = *(const floatx4*)(&S_s[rbase]);
        const int pbase = m0 + rbase;
#pragma unroll
        for (int j = 0; j < 4; j++) {
            const int e = n_w + j * 16 + fr;
            floatx4 o = acc[i][j];
            o.x *= sv.x; o.y *= sv.y; o.z *= sv.z; o.w *= sv.w;
            *(floatx4*)(&outb[(size_t)e * NP + pbase]) = o;
        }
    }
}

extern "C" void kernel_launch(void* const* d_in, const int* in_sizes, int n_in,
                              void* d_out, int out_size, void* d_ws, size_t ws_size,
                              hipStream_t stream) {
    const float* feat = (const float*)d_in[0];   // [4][4096][256] f32
    const float* pos  = (const float*)d_in[1];   // [4][4096][2]  f32
    float* out = (float*)d_out;                  // [4][256][4096] f32
    __half* FT  = (__half*)d_ws;                             // 8.39 MB
    __half* EYf = (__half*)((char*)d_ws + (size_t)NB * NE * NN * 2);   // +2.10 MB

    hipLaunchKernelGGL(feat_transpose, dim3(NN / 32, NE / 32, NB), dim3(32, 8), 0, stream,
                       feat, FT);
    hipLaunchKernelGGL(eyf_kernel, dim3((NB << 18) / 256), dim3(256), 0, stream,
                       pos, EYf);
    hipLaunchKernelGGL(nw_gemm, dim3(NB * (NP / 64)), dim3(512), 0, stream,
                       FT, EYf, pos, out);
}

// Round 3
// 131.926 us; speedup vs baseline: 1.2642x; 1.2642x over previous
//
#include <hip/hip_runtime.h>
#include <hip/hip_fp16.h>

// NeuronToSpatialGrid: out[b,e,p] = (sum_n w * F[b,n,e]) / (sum_n w + EPS),
//   w = exp(-50 dx^2) * exp(-50 dy^2)  (separable).
// R3: 64m x 128e block tiles (grid 512 = 2 blocks/CU for barrier-domain overlap),
// single-barrier K-loop with LDS double-buffer, full-iteration prefetch cover.

typedef __attribute__((ext_vector_type(8))) _Float16 half8;
typedef __attribute__((ext_vector_type(2))) _Float16 half2v;
typedef __attribute__((ext_vector_type(4))) float floatx4;

#define NB 4
#define NN 4096
#define NE 256
#define NP 4096

#if defined(__has_builtin)
#if __has_builtin(__builtin_amdgcn_fdot2)
#define HAVE_FDOT2 1
#endif
#endif

__device__ inline float sum8(half8 v, float s) {
#ifdef HAVE_FDOT2
    half2v one; one[0] = (_Float16)1.0f; one[1] = (_Float16)1.0f;
    half2v* p = (half2v*)&v;
#pragma unroll
    for (int j = 0; j < 4; j++) s = __builtin_amdgcn_fdot2(p[j], one, s, false);
#else
#pragma unroll
    for (int j = 0; j < 8; j++) s += (float)v[j];
#endif
    return s;
}

#define MFMA16(a, bb, c) __builtin_amdgcn_mfma_f32_16x16x32_f16(a, bb, c, 0, 0, 0)

// ---------- kernel 1: F [B][N][E] f32 -> FT [B][E][N] f16.
// Tile 128n x 32e.  Reads: float4 (128B segs).  Writes: half2, 64 lanes
// n-consecutive -> 256B segments (R2 version had 64B segs).
__global__ __launch_bounds__(256) void feat_transpose(const float* __restrict__ in,
                                                      __half* __restrict__ ft) {
    __shared__ float tile[128][33];
    const int b  = blockIdx.z;
    const int n0 = blockIdx.x * 128;
    const int e0 = blockIdx.y * 32;
    const int tid = threadIdx.x;
    const int rn = tid >> 3, re = (tid & 7) * 4;
#pragma unroll
    for (int p = 0; p < 4; p++) {
        const int n = p * 32 + rn;
        float4 v = *(const float4*)&in[(size_t)(b * NN + n0 + n) * NE + e0 + re];
        tile[n][re] = v.x; tile[n][re + 1] = v.y; tile[n][re + 2] = v.z; tile[n][re + 3] = v.w;
    }
    __syncthreads();
    const int we = tid >> 6, wn = (tid & 63) * 2;
#pragma unroll
    for (int p = 0; p < 8; p++) {
        const int e = p * 4 + we;
        __half2 h = __floats2half2_rn(tile[wn][e], tile[wn + 1][e]);
        *(__half2*)&ft[(size_t)(b * NE + e0 + e) * NN + n0 + wn] = h;
    }
}

// ---------- kernel 2: EY in MFMA-A-frag order [b][kb128][rb4][quad4][fr16][j8],
// value exp(-50*(r/63 - y_k)^2), r = rb*16+fr, k = kb*32+quad*8+j.
__global__ __launch_bounds__(256) void eyf_kernel(const float* __restrict__ pos,
                                                  __half* __restrict__ EYf) {
    const int idx = blockIdx.x * 256 + threadIdx.x;
    const int j    = idx & 7;
    const int fr   = (idx >> 3) & 15;
    const int quad = (idx >> 7) & 3;
    const int rb   = (idx >> 9) & 3;
    const int kb   = (idx >> 11) & 127;
    const int b    = idx >> 18;
    const int r = rb * 16 + fr;
    const int k = kb * 32 + quad * 8 + j;
    const float y = pos[((size_t)b * NN + k) * 2 + 1];
    const float d = (float)r * (1.0f / 63.0f) - y;
    EYf[idx] = __float2half_rn(__expf(d * d * -50.0f));
}

// ---------- kernel 3: fused GEMM.  grid 512 (2 blocks/CU), 256 thr (4 waves 2m x 2n).
// Tile 64m x 128e x BK=32.  A-frags in regs (ex*ey); B double-buffered in LDS,
// ONE __syncthreads per K-step; prefetch has a full iteration of vmcnt cover.
__global__ __launch_bounds__(256, 2) void nw_gemm(const __half* __restrict__ FT,   // [B][E][N]
                                                  const __half* __restrict__ EYf,  // frag order
                                                  const float* __restrict__ pos,   // [B][N][2]
                                                  float* __restrict__ out) {       // [B][E][P]
    __shared__ __half Bt_s[2][128][40];   // 20 KB double-buffered feature tile
    __shared__ __half ex_s[NN];           // 8 KB
    __shared__ float S_s[64];

    const int bid = blockIdx.x;
    const int xcd = bid & 7;              // (b, et) pinned per XCD: 1.5MB working set in L2
    const int b   = xcd >> 1;
    const int et  = xcd & 1;
    const int mt  = bid >> 3;             // 0..63
    const int m0  = mt * 64;
    const int tid = threadIdx.x;

    // ex_s: 4096 exps once per block (gx = mt constant)
    {
        const float gxv = (float)mt * (1.0f / 63.0f);
        const float* pb = pos + (size_t)b * NN * 2;
        for (int k = tid; k < NN; k += 256) {
            float d = gxv - pb[2 * k];
            ex_s[k] = __float2half_rn(__expf(d * d * -50.0f));
        }
    }

    // B staging: thread -> e-row tid>>1 (of 128), k-half (tid&1)*16
    const int brow = tid >> 1;
    const int bh   = tid & 1;
    const __half* bsrc = FT + ((size_t)b * NE + et * 128 + brow) * NN + bh * 16;

    // waves: 2(m-groups of 32 rows) x 2(n-groups of 64 e)
    const int wave = tid >> 6, lane = tid & 63;
    const int g   = wave >> 1;
    const int n_w = (wave & 1) * 64;
    const int fr = lane & 15, quad = lane >> 4;
    const int quad8 = quad * 8;

    const __half* eyb = EYf + ((size_t)b << 18) + quad * 128 + fr * 8;
    const __half* ey0p = eyb + (g * 2 + 0) * 512;   // + ks*64 per K-step
    const __half* ey1p = eyb + (g * 2 + 1) * 512;

    const bool sumwave = (wave & 1) == 0;

    floatx4 acc[2][4] = {};
    float s0 = 0.f, s1 = 0.f;

    // prologue: stage tile0 -> buf0; prefetch tile1 + ey(0), ey(32)
    uint4 bv0 = *(const uint4*)(bsrc);
    uint4 bv1 = *(const uint4*)(bsrc + 8);
    half8 eyA0 = *(const half8*)(ey0p);
    half8 eyA1 = *(const half8*)(ey1p);
    half8 eyB0 = *(const half8*)(ey0p + 32 * 64);
    half8 eyB1 = *(const half8*)(ey1p + 32 * 64);

    *(uint4*)(&Bt_s[0][brow][bh * 16])     = bv0;
    *(uint4*)(&Bt_s[0][brow][bh * 16 + 8]) = bv1;
    bv0 = *(const uint4*)(bsrc + 32);
    bv1 = *(const uint4*)(bsrc + 40);

    for (int ks = 0; ks < NN; ks += 64) {
        // ---- sub A: compute tile(ks) from buf0; stage tile(ks+32) -> buf1 ----
        __syncthreads();
        *(uint4*)(&Bt_s[1][brow][bh * 16])     = bv0;
        *(uint4*)(&Bt_s[1][brow][bh * 16 + 8]) = bv1;
        {
            const int kc = (ks + 64 < NN) ? ks + 64 : 0;
            bv0 = *(const uint4*)(bsrc + kc);
            bv1 = *(const uint4*)(bsrc + kc + 8);
        }
        {
            half8 ex8 = *(const half8*)(&ex_s[ks + quad8]);
            half8 af0 = ex8 * eyA0;
            half8 af1 = ex8 * eyA1;
            if (sumwave) { s0 = sum8(af0, s0); s1 = sum8(af1, s1); }
            half8 bf0 = *(const half8*)(&Bt_s[0][n_w + fr][quad8]);
            half8 bf1 = *(const half8*)(&Bt_s[0][n_w + 16 + fr][quad8]);
            half8 bf2 = *(const half8*)(&Bt_s[0][n_w + 32 + fr][quad8]);
            half8 bf3 = *(const half8*)(&Bt_s[0][n_w + 48 + fr][quad8]);
            acc[0][0] = MFMA16(af0, bf0, acc[0][0]);
            acc[0][1] = MFMA16(af0, bf1, acc[0][1]);
            acc[0][2] = MFMA16(af0, bf2, acc[0][2]);
            acc[0][3] = MFMA16(af0, bf3, acc[0][3]);
            acc[1][0] = MFMA16(af1, bf0, acc[1][0]);
            acc[1][1] = MFMA16(af1, bf1, acc[1][1]);
            acc[1][2] = MFMA16(af1, bf2, acc[1][2]);
            acc[1][3] = MFMA16(af1, bf3, acc[1][3]);
        }
        {
            const int kc = (ks + 64 < NN) ? ks + 64 : 0;
            eyA0 = *(const half8*)(ey0p + kc * 64);
            eyA1 = *(const half8*)(ey1p + kc * 64);
        }

        // ---- sub B: compute tile(ks+32) from buf1; stage tile(ks+64) -> buf0 ----
        __syncthreads();
        *(uint4*)(&Bt_s[0][brow][bh * 16])     = bv0;
        *(uint4*)(&Bt_s[0][brow][bh * 16 + 8]) = bv1;
        {
            const int kc = (ks + 96 < NN) ? ks + 96 : 0;
            bv0 = *(const uint4*)(bsrc + kc);
            bv1 = *(const uint4*)(bsrc + kc + 8);
        }
        {
            half8 ex8 = *(const half8*)(&ex_s[ks + 32 + quad8]);
            half8 af0 = ex8 * eyB0;
            half8 af1 = ex8 * eyB1;
            if (sumwave) { s0 = sum8(af0, s0); s1 = sum8(af1, s1); }
            half8 bf0 = *(const half8*)(&Bt_s[1][n_w + fr][quad8]);
            half8 bf1 = *(const half8*)(&Bt_s[1][n_w + 16 + fr][quad8]);
            half8 bf2 = *(const half8*)(&Bt_s[1][n_w + 32 + fr][quad8]);
            half8 bf3 = *(const half8*)(&Bt_s[1][n_w + 48 + fr][quad8]);
            acc[0][0] = MFMA16(af0, bf0, acc[0][0]);
            acc[0][1] = MFMA16(af0, bf1, acc[0][1]);
            acc[0][2] = MFMA16(af0, bf2, acc[0][2]);
            acc[0][3] = MFMA16(af0, bf3, acc[0][3]);
            acc[1][0] = MFMA16(af1, bf0, acc[1][0]);
            acc[1][1] = MFMA16(af1, bf1, acc[1][1]);
            acc[1][2] = MFMA16(af1, bf2, acc[1][2]);
            acc[1][3] = MFMA16(af1, bf3, acc[1][3]);
        }
        {
            const int kc = (ks + 96 < NN) ? ks + 96 : 0;
            eyB0 = *(const half8*)(ey0p + kc * 64);
            eyB1 = *(const half8*)(ey1p + kc * 64);
        }
    }

    // row sums (k split as quad*8+j over ks steps): reduce across quad
    if (sumwave) {
        s0 += __shfl_xor(s0, 16, 64); s0 += __shfl_xor(s0, 32, 64);
        s1 += __shfl_xor(s1, 16, 64); s1 += __shfl_xor(s1, 32, 64);
        if (quad == 0) {
            S_s[g * 32 + fr]      = 1.0f / (s0 + 1e-8f);
            S_s[g * 32 + 16 + fr] = 1.0f / (s1 + 1e-8f);
        }
    }
    __syncthreads();

    // epilogue: normalize, float4 stores along p
    float* outb = out + (size_t)b * NE * NP;
    const int m_w = g * 32;
#pragma unroll
    for (int i = 0; i < 2; i++) {
        const int rbase = m_w + i * 16 + quad * 4;
        floatx4 sv = *(const floatx4*)(&S_s[rbase]);
        const int pbase = m0 + rbase;
#pragma unroll
        for (int j = 0; j < 4; j++) {
            const int e = et * 128 + n_w + j * 16 + fr;
            floatx4 o = acc[i][j];
            o.x *= sv.x; o.y *= sv.y; o.z *= sv.z; o.w *= sv.w;
            *(floatx4*)(&outb[(size_t)e * NP + pbase]) = o;
        }
    }
}

extern "C" void kernel_launch(void* const* d_in, const int* in_sizes, int n_in,
                              void* d_out, int out_size, void* d_ws, size_t ws_size,
                              hipStream_t stream) {
    const float* feat = (const float*)d_in[0];   // [4][4096][256] f32
    const float* pos  = (const float*)d_in[1];   // [4][4096][2]  f32
    float* out = (float*)d_out;                  // [4][256][4096] f32
    __half* FT  = (__half*)d_ws;                             // 8.39 MB
    __half* EYf = (__half*)((char*)d_ws + (size_t)NB * NE * NN * 2);   // +2.10 MB

    hipLaunchKernelGGL(feat_transpose, dim3(NN / 128, NE / 32, NB), dim3(256), 0, stream,
                       feat, FT);
    hipLaunchKernelGGL(eyf_kernel, dim3((NB << 18) / 256), dim3(256), 0, stream,
                       pos, EYf);
    hipLaunchKernelGGL(nw_gemm, dim3(NB * (NP / 64) * 2), dim3(256), 0, stream,
                       FT, EYf, pos, out);
}